// Round 4
// baseline (35957.306 us; speedup 1.0000x reference)
//
#include <hip/hip_runtime.h>
#include <hip/hip_cooperative_groups.h>
#include <stdint.h>

namespace cg = cooperative_groups;

// ============================================================================
// CharNN: 2-layer GRU char LM (B=64, T=512, V=256, E=H=1024) on MI355X.
// Round 4 strategy:
//  * ONE persistent cooperative kernel runs the whole recurrence: 256 blocks,
//    W1 (32KB) + fused W2 (64KB) fp16 images resident in LDS for all 512 steps
//  * layers pipelined: interval i does layer1[t=i] and layer2[t=i-1] -> 513
//    grid.sync()s total (vs 1024 kernel launches in round 3)
//  * layer-2 input GEMM fused as K=2048 over [h2 ; y1]; y1 IS the h1 ping-pong
//    buffer (no y1 storage, no gx2 GEMM, no chunking). n-gate h/x halves kept
//    in separate accumulators to preserve r*(W_hh.h+b) semantics.
//  * fp16 single-pass numerics everywhere (was 3-term split-bf16): h in (-1,1),
//    |W|<0.25 -> fp16 rel err 2.4e-4; predicted absmax ~5e-3 << 0.028
//  * G0 trick: layer-1 input gates = gather of (emb @ W_ih0^T + b_ih0)[X]
// ============================================================================

namespace {

constexpr int B = 64, T = 512, V = 256, H = 1024, G = 3072;  // G = 3*H

typedef _Float16 f16;
typedef f16 f16x8 __attribute__((ext_vector_type(8)));
typedef f16 f16x4 __attribute__((ext_vector_type(4)));
typedef float f32x4 __attribute__((ext_vector_type(4)));

// ---- fp32 -> fp16 convert (x4 vectorized) ----------------------------------
__global__ void to_f16_4(const float* __restrict__ src, f16* __restrict__ dst,
                         int n4) {
  int i = blockIdx.x * 256 + threadIdx.x;
  if (i >= n4) return;
  float4 v = reinterpret_cast<const float4*>(src)[i];
  f16x4 o = {(f16)v.x, (f16)v.y, (f16)v.z, (f16)v.w};
  reinterpret_cast<f16x4*>(dst)[i] = o;
}

// ---- pack W_hh[0] into per-block LDS images --------------------------------
// pW1 flat id = ((bx*32 + k0)*16 + row)*32 + kk ; block bx owns j in
// [bx*4, bx*4+4). row: 0-3 = r-gate j0..3, 4-7 = z, 8-11 = n, 12-15 = pad.
__global__ void pack_w1(const float* __restrict__ Whh, f16* __restrict__ pW1) {
  const int id = blockIdx.x * 256 + threadIdx.x;  // 4,194,304 total
  const int kk = id & 31, row = (id >> 5) & 15, k0 = (id >> 9) & 31,
            bx = id >> 14;
  float v = 0.f;
  if (row < 12) {
    const int ridx = (row >> 2) * H + bx * 4 + (row & 3);
    v = Whh[(size_t)ridx * H + k0 * 32 + kk];
  }
  pW1[id] = (f16)v;
}

// ---- pack fused [W_hh[1] | W_ih[1]] (K=2048) into per-block LDS images -----
// pW2 flat id = ((bx*64 + k0)*16 + row)*32 + kk ; k = k0*32+kk; k<1024 -> W_hh.
__global__ void pack_w2(const float* __restrict__ Whh,
                        const float* __restrict__ Wih, f16* __restrict__ pW2) {
  const int id = blockIdx.x * 256 + threadIdx.x;  // 8,388,608 total
  const int kk = id & 31, row = (id >> 5) & 15, k0 = (id >> 9) & 63,
            bx = id >> 15;
  float v = 0.f;
  if (row < 12) {
    const int ridx = (row >> 2) * H + bx * 4 + (row & 3);
    const int k = k0 * 32 + kk;
    v = (k < 1024) ? Whh[(size_t)G * H + (size_t)ridx * H + k]
                   : Wih[(size_t)G * H + (size_t)ridx * H + (k - 1024)];
  }
  pW2[id] = (f16)v;
}

// ---- pack h0 into h-state tile layout [k0][b][kk] fp16 ---------------------
__global__ void pack_h0f(const float* __restrict__ h0, f16* __restrict__ h1,
                         f16* __restrict__ h2) {
  const int id = blockIdx.x * 256 + threadIdx.x;  // 131072
  const int layer = id >> 16, b = (id >> 10) & 63, j = id & 1023;
  const size_t a = ((size_t)(j >> 5) * 64 + b) * 32 + (j & 31);
  const f16 v = (f16)h0[id];
  if (layer == 0) h1[a] = v; else h2[a] = v;
}

// ---- fp16 GEMM: C[M,N] = A[M,K] @ B[N,K]^T + bias --------------------------
// MODE 0: C fp32 row-major. MODE 2: logits epilogue: m = t*64+b (y2 row
// order), write out[(b*(T-1)+t)*V + n] for t < T-1.
template <int MODE>
__global__ __launch_bounds__(256) void gemm_f16(
    const f16* __restrict__ A, const f16* __restrict__ Bm,
    const float* __restrict__ bias, float* __restrict__ C, int M, int N,
    int K) {
  __shared__ __align__(16) f16 As[64][48], Bs[64][48];

  const int tid = threadIdx.x;
  const int lane = tid & 63, wv = tid >> 6;
  const int bm = blockIdx.y, bn = blockIdx.x;
  const int srow = tid >> 2, sseg = (tid & 3) * 8;

  const f16* pA = A + (size_t)(bm * 64 + srow) * K + sseg;
  const f16* pB = Bm + (size_t)(bn * 64 + srow) * K + sseg;

  f32x4 acc[4];
  const f32x4 zero = {0.f, 0.f, 0.f, 0.f};
#pragma unroll
  for (int nt = 0; nt < 4; ++nt) acc[nt] = zero;

  const int ar = wv * 16 + (lane & 15);
  const int kk = (lane >> 4) * 8;

  for (int k0 = 0; k0 < K; k0 += 32) {
    int4 va = *reinterpret_cast<const int4*>(pA + k0);
    int4 vb = *reinterpret_cast<const int4*>(pB + k0);
    __syncthreads();
    *reinterpret_cast<int4*>(&As[srow][sseg]) = va;
    *reinterpret_cast<int4*>(&Bs[srow][sseg]) = vb;
    __syncthreads();

    f16x8 av = *reinterpret_cast<const f16x8*>(&As[ar][kk]);
#pragma unroll
    for (int nt = 0; nt < 4; ++nt) {
      f16x8 bv = *reinterpret_cast<const f16x8*>(&Bs[nt * 16 + (lane & 15)][kk]);
      acc[nt] = __builtin_amdgcn_mfma_f32_16x16x32_f16(av, bv, acc[nt], 0, 0, 0);
    }
  }

  // C/D layout: col = lane&15, row = (lane>>4)*4 + reg  (m89-verified)
  const int rbase = wv * 16 + (lane >> 4) * 4;
  const int cl = lane & 15;
#pragma unroll
  for (int nt = 0; nt < 4; ++nt) {
    const int n = bn * 64 + nt * 16 + cl;
    const float bv = bias[n];
#pragma unroll
    for (int r = 0; r < 4; ++r) {
      const int m = bm * 64 + rbase + r;
      const float v = acc[nt][r] + bv;
      if (MODE == 0) {
        C[(size_t)m * N + n] = v;
      } else {
        const int t = m >> 6, bb = m & 63;
        if (t < T - 1) C[((size_t)(bb * (T - 1) + t)) * V + n] = v;
      }
    }
  }
}

// ---- persistent GRU: both layers, all 512 steps, one launch ----------------
// 256 blocks x 256 threads, cooperative. Block bx owns j in [bx*4, bx*4+4).
// Interval i: layer1 computes t=i (i<512); layer2 computes t=i-1 (i>0).
// h1 state doubles as y1 (layer-2 fused input reads h1buf directly).
__global__ __launch_bounds__(256, 1) void gru_persistent(
    const f16* __restrict__ pW1, const f16* __restrict__ pW2,
    const float* __restrict__ G0, const int* __restrict__ X,
    const float* __restrict__ b_hh, const float* __restrict__ b_ih,
    f16* __restrict__ h1a, f16* __restrict__ h1b, f16* __restrict__ h2a,
    f16* __restrict__ h2b, f16* __restrict__ y2) {
  __shared__ __align__(16) f16 W1t[16384];  // 32 KB: [k0<32][row16][kk32]
  __shared__ __align__(16) f16 W2t[32768];  // 64 KB: [k0<64][row16][kk32]

  const int tid = threadIdx.x, bx = blockIdx.x;
  const int lane = tid & 63, wv = tid >> 6;
  const int l15 = lane & 15, kq = lane >> 4;

  // ---- stage both W images once ----
  {
    const int4* s1 = reinterpret_cast<const int4*>(pW1 + (size_t)bx * 16384);
    int4* d1 = reinterpret_cast<int4*>(W1t);
#pragma unroll
    for (int q = 0; q < 8; ++q) d1[q * 256 + tid] = s1[q * 256 + tid];
    const int4* s2 = reinterpret_cast<const int4*>(pW2 + (size_t)bx * 32768);
    int4* d2 = reinterpret_cast<int4*>(W2t);
#pragma unroll
    for (int q = 0; q < 16; ++q) d2[q * 256 + tid] = s2[q * 256 + tid];
  }
  __syncthreads();

  f16* h1buf[2] = {h1a, h1b};
  f16* h2buf[2] = {h2a, h2b};

  const int aoff = (wv * 16 + l15) * 32 + kq * 8;  // A-frag offset in tile slab
  const f16* w1p = W1t + l15 * 32 + kq * 8;
  const f16* w2p = W2t + l15 * 32 + kq * 8;
  const int jj = l15;
  const int j = bx * 4 + (jj & 3);
  // per-lane bias preload (valid for jj<4 lanes; harmless otherwise)
  const float bhr1 = b_hh[j], bhz1 = b_hh[H + j], bhn1 = b_hh[2 * H + j];
  const float bhr2 = b_hh[G + j], bhz2 = b_hh[G + H + j], bhn2 = b_hh[G + 2 * H + j];
  const float bir2 = b_ih[G + j], biz2 = b_ih[G + H + j], bin2 = b_ih[G + 2 * H + j];
  const size_t haddr0 = (size_t)(j >> 5) * 2048 + (j & 31);  // + b*32

  cg::grid_group grid = cg::this_grid();

  for (int i = 0; i <= T; ++i) {
    f32x4 acc1 = {0.f, 0.f, 0.f, 0.f};
    f32x4 acc2 = {0.f, 0.f, 0.f, 0.f};  // layer2 W_hh half
    f32x4 acc3 = {0.f, 0.f, 0.f, 0.f};  // layer2 W_ih half

    if (i < T) {  // layer-1 K-loop (K=1024)
      const f16* a = h1buf[i & 1] + aoff;
#pragma unroll 8
      for (int k0 = 0; k0 < 32; ++k0) {
        f16x8 av = *reinterpret_cast<const f16x8*>(a + k0 * 2048);
        f16x8 bv = *reinterpret_cast<const f16x8*>(w1p + k0 * 512);
        acc1 = __builtin_amdgcn_mfma_f32_16x16x32_f16(av, bv, acc1, 0, 0, 0);
      }
    }
    if (i > 0) {  // layer-2 fused K-loops (K=2048)
      const f16* a = h2buf[(i - 1) & 1] + aoff;
#pragma unroll 8
      for (int k0 = 0; k0 < 32; ++k0) {
        f16x8 av = *reinterpret_cast<const f16x8*>(a + k0 * 2048);
        f16x8 bv = *reinterpret_cast<const f16x8*>(w2p + k0 * 512);
        acc2 = __builtin_amdgcn_mfma_f32_16x16x32_f16(av, bv, acc2, 0, 0, 0);
      }
      const f16* a2 = h1buf[i & 1] + aoff;  // y1[t=i-1]
#pragma unroll 8
      for (int k0 = 0; k0 < 32; ++k0) {
        f16x8 av = *reinterpret_cast<const f16x8*>(a2 + k0 * 2048);
        f16x8 bv = *reinterpret_cast<const f16x8*>(w2p + (k0 + 32) * 512);
        acc3 = __builtin_amdgcn_mfma_f32_16x16x32_f16(av, bv, acc3, 0, 0, 0);
      }
    }

    // ---- epilogues (shfl first: all lanes participate) ----
    float z1[4], n1[4], z2h[4], n2h[4], z2x[4], n2x[4];
#pragma unroll
    for (int r = 0; r < 4; ++r) {
      z1[r] = __shfl_xor(acc1[r], 4);
      n1[r] = __shfl_xor(acc1[r], 8);
      z2h[r] = __shfl_xor(acc2[r], 4);
      n2h[r] = __shfl_xor(acc2[r], 8);
      z2x[r] = __shfl_xor(acc3[r], 4);
      n2x[r] = __shfl_xor(acc3[r], 8);
    }
    if (jj < 4) {
      if (i < T) {  // layer-1 epilogue: h1[t=i]
        const f16* hin = h1buf[i & 1];
        f16* hout = h1buf[(i + 1) & 1];
#pragma unroll
        for (int r = 0; r < 4; ++r) {
          const int b = wv * 16 + kq * 4 + r;
          const float* gx = G0 + (size_t)X[b * T + i] * G;
          const float xr = gx[j], xz = gx[H + j], xn = gx[2 * H + j];
          const size_t ha = haddr0 + (size_t)b * 32;
          const float hp = (float)hin[ha];
          const float rg = 1.f / (1.f + __expf(-(xr + acc1[r] + bhr1)));
          const float zg = 1.f / (1.f + __expf(-(xz + z1[r] + bhz1)));
          const float ng = tanhf(xn + rg * (n1[r] + bhn1));
          hout[ha] = (f16)((1.f - zg) * ng + zg * hp);
        }
      }
      if (i > 0) {  // layer-2 epilogue: h2[t=i-1], y2 row
        const int t2 = i - 1;
        const f16* hin = h2buf[(i - 1) & 1];
        f16* hout = h2buf[i & 1];
#pragma unroll
        for (int r = 0; r < 4; ++r) {
          const int b = wv * 16 + kq * 4 + r;
          const size_t ha = haddr0 + (size_t)b * 32;
          const float hp = (float)hin[ha];
          const float rg =
              1.f / (1.f + __expf(-(acc2[r] + acc3[r] + bhr2 + bir2)));
          const float zg =
              1.f / (1.f + __expf(-(z2h[r] + z2x[r] + bhz2 + biz2)));
          const float ng = tanhf(n2x[r] + bin2 + rg * (n2h[r] + bhn2));
          const float hv = (1.f - zg) * ng + zg * hp;
          hout[ha] = (f16)hv;
          y2[((size_t)t2 * 64 + b) * 1024 + j] = (f16)hv;
        }
      }
    }
    __threadfence();
    grid.sync();
  }
}

}  // namespace

// ============================================================================
extern "C" void kernel_launch(void* const* d_in, const int* in_sizes, int n_in,
                              void* d_out, int out_size, void* d_ws,
                              size_t ws_size, hipStream_t stream) {
  const int* X = (const int*)d_in[0];
  const float* h0 = (const float*)d_in[1];
  const float* emb = (const float*)d_in[2];
  const float* W_ih = (const float*)d_in[3];
  const float* W_hh = (const float*)d_in[4];
  const float* b_ih = (const float*)d_in[5];
  const float* b_hh = (const float*)d_in[6];
  const float* W_out = (const float*)d_in[7];
  const float* b_out = (const float*)d_in[8];
  float* out = (float*)d_out;
  (void)in_sizes; (void)n_in; (void)out_size; (void)ws_size;

  // ---- workspace (~99 MB) ----
  char* p = (char*)d_ws;
  auto alloc = [&](size_t bytes) {
    char* q = p;
    p += (bytes + 255) & ~(size_t)255;
    return q;
  };
  f16* pW1 = (f16*)alloc((size_t)256 * 16384 * 2);      // 8 MB
  f16* pW2 = (f16*)alloc((size_t)256 * 32768 * 2);      // 16 MB
  float* G0 = (float*)alloc((size_t)V * G * 4);         // 3 MB
  f16* emb16 = (f16*)alloc((size_t)V * H * 2);          // 0.5 MB
  f16* wih0_16 = (f16*)alloc((size_t)G * H * 2);        // 6 MB
  f16* wout16 = (f16*)alloc((size_t)V * H * 2);         // 0.5 MB
  f16* h1a = (f16*)alloc((size_t)B * H * 2);
  f16* h1b = (f16*)alloc((size_t)B * H * 2);
  f16* h2a = (f16*)alloc((size_t)B * H * 2);
  f16* h2b = (f16*)alloc((size_t)B * H * 2);
  f16* y2 = (f16*)alloc((size_t)T * B * H * 2);         // 64 MB

  // ---- one-time converts / packs / G0 ----
  to_f16_4<<<(V * H / 4 + 255) / 256, 256, 0, stream>>>(emb, emb16, V * H / 4);
  to_f16_4<<<(G * H / 4 + 255) / 256, 256, 0, stream>>>(W_ih, wih0_16,
                                                        G * H / 4);
  to_f16_4<<<(V * H / 4 + 255) / 256, 256, 0, stream>>>(W_out, wout16,
                                                        V * H / 4);
  pack_w1<<<16384, 256, 0, stream>>>(W_hh, pW1);
  pack_w2<<<32768, 256, 0, stream>>>(W_hh, W_ih, pW2);
  pack_h0f<<<512, 256, 0, stream>>>(h0, h1a, h2a);
  gemm_f16<0><<<dim3(G / 64, V / 64), 256, 0, stream>>>(emb16, wih0_16, b_ih,
                                                        G0, V, G, H);

  // ---- persistent recurrence (cooperative) ----
  {
    const f16* a0 = pW1; const f16* a1 = pW2;
    const float* a2 = G0; const int* a3 = X;
    const float* a4 = b_hh; const float* a5 = b_ih;
    f16* a6 = h1a; f16* a7 = h1b; f16* a8 = h2a; f16* a9 = h2b; f16* a10 = y2;
    void* args[] = {&a0, &a1, &a2, &a3, &a4, &a5, &a6, &a7, &a8, &a9, &a10};
    hipLaunchCooperativeKernel((const void*)gru_persistent, dim3(256),
                               dim3(256), args, 0, stream);
  }

  // ---- logits = y2 @ W_out^T + b_out (drop t = T-1 rows) ----
  gemm_f16<2><<<dim3(V / 64, (T * B) / 64), 256, 0, stream>>>(
      y2, wout16, b_out, out, T * B, V, H);
}

// Round 5
// 28782.538 us; speedup vs baseline: 1.2493x; 1.2493x over previous
//
#include <hip/hip_runtime.h>
#include <stdint.h>

// ============================================================================
// CharNN: 2-layer GRU char LM (B=64, T=512, V=256, E=H=1024) on MI355X.
// Round 5: persistent 3-role pipeline with custom flag barrier.
//  * 192 blocks: [0,64) L1 recurrence, [64,128) GX (= y1 @ W_ih1^T producer),
//    [128,192) L2 recurrence. 2-step software pipeline skew, 514 intervals.
//  * custom all-to-all barrier: per-block release-store of bar[bx]=phase,
//    192 pollers acquire-load one slot each (replaces 70us grid.sync -> ~2us)
//  * per block: 16-j tile, 96KB fp16 W image in LDS (rows padded to 36 f16 ->
//    <=2-way bank conflicts), 3 gate accumulators/wave, no shfl in epilogue
//  * h/y2 in tiled [k0][b][kk] layout -> 32B-run coalesced writes (fixes the
//    790MB WRITE_SIZE amplification seen in round 4)
//  * fp16 single-pass numerics (round-4 absmax 0.0078 << 0.028 threshold)
// ============================================================================

namespace {

constexpr int B = 64, T = 512, V = 256, H = 1024, G = 3072;  // G = 3*H
constexpr int NBLK = 192;

typedef _Float16 f16;
typedef f16 f16x8 __attribute__((ext_vector_type(8)));
typedef f16 f16x4 __attribute__((ext_vector_type(4)));
typedef float f32x4 __attribute__((ext_vector_type(4)));

#define MFMA16(av, bv, acc) __builtin_amdgcn_mfma_f32_16x16x32_f16(av, bv, acc, 0, 0, 0)

// ---- fp32 -> fp16 convert (x4 vectorized) ----------------------------------
__global__ void to_f16_4(const float* __restrict__ src, f16* __restrict__ dst,
                         int n4) {
  int i = blockIdx.x * 256 + threadIdx.x;
  if (i >= n4) return;
  float4 v = reinterpret_cast<const float4*>(src)[i];
  f16x4 o = {(f16)v.x, (f16)v.y, (f16)v.z, (f16)v.w};
  reinterpret_cast<f16x4*>(dst)[i] = o;
}

// ---- pack the 3 role weight images -----------------------------------------
// dst[which][bi][k0<32][row<48][kk<32] f16, dense. row = g*16 + jrow,
// j = bi*16 + jrow. which: 0 = W_hh[0], 1 = W_ih[1], 2 = W_hh[1].
__global__ void pack_w(const float* __restrict__ Whh,
                       const float* __restrict__ Wih, f16* __restrict__ dst) {
  const int id = blockIdx.x * 256 + threadIdx.x;  // 1,179,648 vec8 elems
  const int kkq = id & 3;
  const int rr = id >> 2;
  const int row = rr % 48;
  const int rest = rr / 48;
  const int k0 = rest & 31, bi = (rest >> 5) & 63, which = rest >> 11;
  const int g = row >> 4, jrow = row & 15;
  const float* base = (which == 0) ? Whh
                    : (which == 1) ? (Wih + (size_t)G * H)
                                   : (Whh + (size_t)G * H);
  const float* src =
      base + ((size_t)(g * H + bi * 16 + jrow)) * H + k0 * 32 + kkq * 8;
  float4 a = *reinterpret_cast<const float4*>(src);
  float4 b = *reinterpret_cast<const float4*>(src + 4);
  f16x8 o = {(f16)a.x, (f16)a.y, (f16)a.z, (f16)a.w,
             (f16)b.x, (f16)b.y, (f16)b.z, (f16)b.w};
  *reinterpret_cast<f16x8*>(dst + (size_t)id * 8) = o;
}

// ---- pack h0 into tiled layout [k0][b][kk] fp16 ----------------------------
__global__ void pack_h0f(const float* __restrict__ h0, f16* __restrict__ h1,
                         f16* __restrict__ h2) {
  const int id = blockIdx.x * 256 + threadIdx.x;  // 131072
  const int layer = id >> 16, b = (id >> 10) & 63, j = id & 1023;
  const size_t a = ((size_t)(j >> 5) * 64 + b) * 32 + (j & 31);
  const f16 v = (f16)h0[id];
  if (layer == 0) h1[a] = v; else h2[a] = v;
}

// ---- fp16 GEMM: C[M,N] = A @ B[N,K]^T + bias -------------------------------
// MODE 0: A row-major [M,K], C fp32 [M,N].
// MODE 2: logits. A is y2 in tiled per-t slabs ([t][k0][b][kk], 65536/t);
//         bm indexes t; write out[(b*(T-1)+t)*V + n] for t < T-1.
template <int MODE>
__global__ __launch_bounds__(256) void gemm_f16(
    const f16* __restrict__ A, const f16* __restrict__ Bm,
    const float* __restrict__ bias, float* __restrict__ C, int M, int N,
    int K) {
  __shared__ __align__(16) f16 As[64][48], Bs[64][48];

  const int tid = threadIdx.x;
  const int lane = tid & 63, wv = tid >> 6;
  const int bm = blockIdx.y, bn = blockIdx.x;
  const int srow = tid >> 2, sseg = (tid & 3) * 8;

  const f16* pA = (MODE == 2)
                      ? (A + (size_t)bm * 65536 + srow * 32 + sseg)
                      : (A + (size_t)(bm * 64 + srow) * K + sseg);
  const f16* pB = Bm + (size_t)(bn * 64 + srow) * K + sseg;

  f32x4 acc[4];
  const f32x4 zero = {0.f, 0.f, 0.f, 0.f};
#pragma unroll
  for (int nt = 0; nt < 4; ++nt) acc[nt] = zero;

  const int ar = wv * 16 + (lane & 15);
  const int kk = (lane >> 4) * 8;

  const int niter = K / 32;
  for (int ki = 0; ki < niter; ++ki) {
    int4 va = (MODE == 2) ? *reinterpret_cast<const int4*>(pA + ki * 2048)
                          : *reinterpret_cast<const int4*>(pA + ki * 32);
    int4 vb = *reinterpret_cast<const int4*>(pB + ki * 32);
    __syncthreads();
    *reinterpret_cast<int4*>(&As[srow][sseg]) = va;
    *reinterpret_cast<int4*>(&Bs[srow][sseg]) = vb;
    __syncthreads();

    f16x8 av = *reinterpret_cast<const f16x8*>(&As[ar][kk]);
#pragma unroll
    for (int nt = 0; nt < 4; ++nt) {
      f16x8 bv = *reinterpret_cast<const f16x8*>(&Bs[nt * 16 + (lane & 15)][kk]);
      acc[nt] = MFMA16(av, bv, acc[nt]);
    }
  }

  const int rbase = wv * 16 + (lane >> 4) * 4;
  const int cl = lane & 15;
#pragma unroll
  for (int nt = 0; nt < 4; ++nt) {
    const int n = bn * 64 + nt * 16 + cl;
    const float bv = bias[n];
#pragma unroll
    for (int r = 0; r < 4; ++r) {
      const int m = bm * 64 + rbase + r;
      const float v = acc[nt][r] + bv;
      if (MODE == 0) {
        C[(size_t)m * N + n] = v;
      } else {
        const int t = m >> 6, bb = m & 63;
        if (t < T - 1) C[((size_t)(bb * (T - 1) + t)) * V + n] = v;
      }
    }
  }
}

// ---- persistent 3-role GRU pipeline ----------------------------------------
// 192 blocks x 256 threads (cooperative). role = bx>>6, jb = bx&63.
// Interval i: L1 computes h1[t=i] (i<512); GX computes gx2[t=i-1] (1<=i<=512);
// L2 computes h2[t=i-2] + y2 row (2<=i<=513).
__global__ __launch_bounds__(256, 1) void gru_persist(
    const f16* __restrict__ pW, const float* __restrict__ G0,
    const int* __restrict__ X, const float* __restrict__ b_hh,
    const float* __restrict__ b_ih, f16* __restrict__ h1a,
    f16* __restrict__ h1b, f16* __restrict__ h2a, f16* __restrict__ h2b,
    float* __restrict__ gx2, f16* __restrict__ y2, int* __restrict__ bar) {
  __shared__ __align__(16) f16 Wt[55296];  // [k0<32][row<48][kk padded to 36]

  const int tid = threadIdx.x, bx = blockIdx.x;
  const int lane = tid & 63, wv = tid >> 6;
  const int l15 = lane & 15, kq = lane >> 4;
  const int role = bx >> 6, jb = bx & 63;

  // ---- stage this block's 96KB W image (dense global -> padded LDS) ----
  {
    const int2* src = reinterpret_cast<const int2*>(pW + (size_t)bx * 49152);
#pragma unroll
    for (int q = 0; q < 48; ++q) {
      const int flat = q * 256 + tid;   // 12288 int2
      const int k0r = flat >> 3, seg = flat & 7;
      *reinterpret_cast<int2*>(&Wt[k0r * 36 + seg * 4]) = src[flat];
    }
  }
  __syncthreads();

  const int j = jb * 16 + l15;
  float br_ = 0.f, bz_ = 0.f, bn_ = 0.f, bxr_ = 0.f, bxz_ = 0.f, bxn_ = 0.f;
  if (role == 0) {
    br_ = b_hh[j]; bz_ = b_hh[H + j]; bn_ = b_hh[2 * H + j];
  } else if (role == 2) {
    br_ = b_hh[G + j]; bz_ = b_hh[G + H + j]; bn_ = b_hh[G + 2 * H + j];
    bxr_ = b_ih[G + j]; bxz_ = b_ih[G + H + j]; bxn_ = b_ih[G + 2 * H + j];
  }

  f16* h1buf[2] = {h1a, h1b};
  f16* h2buf[2] = {h2a, h2b};
  const int aoff = (wv * 16 + l15) * 32 + kq * 8;
  const f16* wp = Wt + l15 * 36 + kq * 8;  // + k0*1728 + g*576
  const int bB = wv * 16 + kq * 4;
  const size_t hoff = (size_t)(j >> 5) * 2048 + (j & 31);

  for (int i = 0; i <= T + 1; ++i) {
    if (role == 0) {
      if (i < T) {  // ---- L1: h1[t=i] ----
        const f16* hin = h1buf[i & 1];
        f16* hout = h1buf[(i + 1) & 1];
        const f16* a = hin + aoff;
        f32x4 aR = {0, 0, 0, 0}, aZ = {0, 0, 0, 0}, aN = {0, 0, 0, 0};
#pragma unroll 8
        for (int k0 = 0; k0 < 32; ++k0) {
          f16x8 av = *reinterpret_cast<const f16x8*>(a + k0 * 2048);
          const f16* w = wp + k0 * 1728;
          aR = MFMA16(av, *reinterpret_cast<const f16x8*>(w), aR);
          aZ = MFMA16(av, *reinterpret_cast<const f16x8*>(w + 576), aZ);
          aN = MFMA16(av, *reinterpret_cast<const f16x8*>(w + 1152), aN);
        }
#pragma unroll
        for (int r = 0; r < 4; ++r) {
          const int b = bB + r;
          const float* gx = G0 + (size_t)X[b * T + i] * G;
          const float xr = gx[j], xz = gx[H + j], xn = gx[2 * H + j];
          const size_t ha = hoff + (size_t)b * 32;
          const float hp = (float)hin[ha];
          const float rg = 1.f / (1.f + __expf(-(xr + aR[r] + br_)));
          const float zg = 1.f / (1.f + __expf(-(xz + aZ[r] + bz_)));
          const float ng = tanhf(xn + rg * (aN[r] + bn_));
          hout[ha] = (f16)((1.f - zg) * ng + zg * hp);
        }
      }
    } else if (role == 1) {
      if (i >= 1 && i <= T) {  // ---- GX: gx2[t=i-1] = y1[t] @ W_ih1^T ----
        const int t = i - 1;
        const f16* a = h1buf[i & 1] + aoff;  // y1[t] = h1 after step t
        f32x4 aR = {0, 0, 0, 0}, aZ = {0, 0, 0, 0}, aN = {0, 0, 0, 0};
#pragma unroll 8
        for (int k0 = 0; k0 < 32; ++k0) {
          f16x8 av = *reinterpret_cast<const f16x8*>(a + k0 * 2048);
          const f16* w = wp + k0 * 1728;
          aR = MFMA16(av, *reinterpret_cast<const f16x8*>(w), aR);
          aZ = MFMA16(av, *reinterpret_cast<const f16x8*>(w + 576), aZ);
          aN = MFMA16(av, *reinterpret_cast<const f16x8*>(w + 1152), aN);
        }
        float* gdst = gx2 + ((size_t)(t & 1) * 64 + jb) * 3072;
#pragma unroll
        for (int r = 0; r < 4; ++r) {
          const int b = bB + r;
          gdst[b * 16 + l15] = aR[r];
          gdst[1024 + b * 16 + l15] = aZ[r];
          gdst[2048 + b * 16 + l15] = aN[r];
        }
      }
    } else {
      if (i >= 2) {  // ---- L2: h2[t=i-2] + y2 ----
        const int t = i - 2;
        const f16* hin = h2buf[i & 1];
        f16* hout = h2buf[(i + 1) & 1];
        const float* gsrc = gx2 + ((size_t)(t & 1) * 64 + jb) * 3072;
        const f16* a = hin + aoff;
        f32x4 aR = {0, 0, 0, 0}, aZ = {0, 0, 0, 0}, aN = {0, 0, 0, 0};
#pragma unroll 8
        for (int k0 = 0; k0 < 32; ++k0) {
          f16x8 av = *reinterpret_cast<const f16x8*>(a + k0 * 2048);
          const f16* w = wp + k0 * 1728;
          aR = MFMA16(av, *reinterpret_cast<const f16x8*>(w), aR);
          aZ = MFMA16(av, *reinterpret_cast<const f16x8*>(w + 576), aZ);
          aN = MFMA16(av, *reinterpret_cast<const f16x8*>(w + 1152), aN);
        }
#pragma unroll
        for (int r = 0; r < 4; ++r) {
          const int b = bB + r;
          const float xr = gsrc[b * 16 + l15];
          const float xz = gsrc[1024 + b * 16 + l15];
          const float xn = gsrc[2048 + b * 16 + l15];
          const size_t ha = hoff + (size_t)b * 32;
          const float hp = (float)hin[ha];
          const float rg = 1.f / (1.f + __expf(-(xr + bxr_ + aR[r] + br_)));
          const float zg = 1.f / (1.f + __expf(-(xz + bxz_ + aZ[r] + bz_)));
          const float ng = tanhf(xn + bxn_ + rg * (aN[r] + bn_));
          const float hv = (1.f - zg) * ng + zg * hp;
          hout[ha] = (f16)hv;
          y2[(size_t)t * 65536 + ha] = (f16)hv;
        }
      }
    }

    // ---- flat flag barrier (release h/gx writes, acquire for next read) ----
    __threadfence();
    __syncthreads();
    const int ph = i + 1;
    if (tid == 0)
      __hip_atomic_store(&bar[bx], ph, __ATOMIC_RELEASE,
                         __HIP_MEMORY_SCOPE_AGENT);
    if (tid < NBLK) {
      while (__hip_atomic_load(&bar[tid], __ATOMIC_ACQUIRE,
                               __HIP_MEMORY_SCOPE_AGENT) < ph) {
        __builtin_amdgcn_s_sleep(1);
      }
    }
    __syncthreads();
    __threadfence();
  }
}

}  // namespace

// ============================================================================
extern "C" void kernel_launch(void* const* d_in, const int* in_sizes, int n_in,
                              void* d_out, int out_size, void* d_ws,
                              size_t ws_size, hipStream_t stream) {
  const int* X = (const int*)d_in[0];
  const float* h0 = (const float*)d_in[1];
  const float* emb = (const float*)d_in[2];
  const float* W_ih = (const float*)d_in[3];
  const float* W_hh = (const float*)d_in[4];
  const float* b_ih = (const float*)d_in[5];
  const float* b_hh = (const float*)d_in[6];
  const float* W_out = (const float*)d_in[7];
  const float* b_out = (const float*)d_in[8];
  float* out = (float*)d_out;
  (void)in_sizes; (void)n_in; (void)out_size; (void)ws_size;

  // ---- workspace (~94 MB) ----
  char* p = (char*)d_ws;
  auto alloc = [&](size_t bytes) {
    char* q = p;
    p += (bytes + 255) & ~(size_t)255;
    return q;
  };
  f16* pW = (f16*)alloc((size_t)3 * 64 * 49152 * 2);  // 18 MB (3 role images)
  float* G0 = (float*)alloc((size_t)V * G * 4);       // 3 MB
  f16* emb16 = (f16*)alloc((size_t)V * H * 2);
  f16* wih0_16 = (f16*)alloc((size_t)G * H * 2);      // 6 MB
  f16* wout16 = (f16*)alloc((size_t)V * H * 2);
  f16* h1a = (f16*)alloc((size_t)B * H * 2);
  f16* h1b = (f16*)alloc((size_t)B * H * 2);
  f16* h2a = (f16*)alloc((size_t)B * H * 2);
  f16* h2b = (f16*)alloc((size_t)B * H * 2);
  float* gx2 = (float*)alloc((size_t)2 * 64 * 3072 * 4);  // 1.5 MB
  f16* y2 = (f16*)alloc((size_t)T * B * H * 2);           // 64 MB
  int* bar = (int*)alloc(256 * 4);

  // ---- one-time converts / packs / G0 ----
  to_f16_4<<<(V * H / 4 + 255) / 256, 256, 0, stream>>>(emb, emb16, V * H / 4);
  to_f16_4<<<(G * H / 4 + 255) / 256, 256, 0, stream>>>(W_ih, wih0_16,
                                                        G * H / 4);
  to_f16_4<<<(V * H / 4 + 255) / 256, 256, 0, stream>>>(W_out, wout16,
                                                        V * H / 4);
  pack_w<<<4608, 256, 0, stream>>>(W_hh, W_ih, pW);
  pack_h0f<<<512, 256, 0, stream>>>(h0, h1a, h2a);
  gemm_f16<0><<<dim3(G / 64, V / 64), 256, 0, stream>>>(emb16, wih0_16, b_ih,
                                                        G0, V, G, H);

  // ---- persistent 3-role pipeline (cooperative: guarantees co-residency) ----
  {
    const f16* a0 = pW; const float* a1 = G0; const int* a2 = X;
    const float* a3 = b_hh; const float* a4 = b_ih;
    f16* a5 = h1a; f16* a6 = h1b; f16* a7 = h2a; f16* a8 = h2b;
    float* a9 = gx2; f16* a10 = y2; int* a11 = bar;
    void* args[] = {&a0, &a1, &a2, &a3, &a4, &a5, &a6,
                    &a7, &a8, &a9, &a10, &a11};
    hipLaunchCooperativeKernel((const void*)gru_persist, dim3(NBLK), dim3(256),
                               args, 0, stream);
  }

  // ---- logits = y2 @ W_out^T + b_out (drop t = T-1 rows) ----
  gemm_f16<2><<<dim3(V / 64, T), 256, 0, stream>>>(y2, wout16, b_out, out,
                                                   T * B, V, H);
}

// Round 6
// 10110.011 us; speedup vs baseline: 3.5566x; 2.8469x over previous
//
#include <hip/hip_runtime.h>
#include <stdint.h>

// ============================================================================
// CharNN: 2-layer GRU char LM (B=64, T=512, V=256, E=H=1024) on MI355X.
// Round 6: fence-free persistent pipeline.
//  * Round-5 structure kept (3 roles x 64 blocks, 16-j tiles, 96KB LDS W
//    images, 514 intervals) but ALL cross-block state (h1/h2/gx2/flags) is
//    accessed via RELAXED agent-scope atomics = global_load/store with
//    sc0|sc1 (bypass L1+L2, coherent at LLC) -> NO buffer_wbl2 / buffer_inv.
//  * All __threadfence() removed. Ordering: __syncthreads drains each wave's
//    vmcnt (stores acked at coherent point) before tid0's flag store; pollers
//    use relaxed loads (no per-iteration L2 invalidate, unlike round 5).
//  * Round-5 measured 60us/interval = coherence-fence cost; predicted ~4-5us.
//  * Read-only data (G0, X, W images, biases) now stays hot in L2 forever.
// ============================================================================

namespace {

constexpr int B = 64, T = 512, V = 256, H = 1024, G = 3072;  // G = 3*H
constexpr int NBLK = 192;

typedef _Float16 f16;
typedef unsigned long long u64;
typedef f16 f16x8 __attribute__((ext_vector_type(8)));
typedef f16 f16x4 __attribute__((ext_vector_type(4)));
typedef float f32x4 __attribute__((ext_vector_type(4)));

#define MFMA16(av, bv, acc) __builtin_amdgcn_mfma_f32_16x16x32_f16(av, bv, acc, 0, 0, 0)

// ---- relaxed agent-scope (LLC-coherent, no-fence) access helpers -----------
__device__ __forceinline__ f16x8 aload16(const f16* p) {
  u64 lo = __hip_atomic_load(reinterpret_cast<const u64*>(p), __ATOMIC_RELAXED,
                             __HIP_MEMORY_SCOPE_AGENT);
  u64 hi = __hip_atomic_load(reinterpret_cast<const u64*>(p) + 1,
                             __ATOMIC_RELAXED, __HIP_MEMORY_SCOPE_AGENT);
  union { u64 q[2]; f16x8 v; } u;
  u.q[0] = lo; u.q[1] = hi;
  return u.v;
}
__device__ __forceinline__ float aload2(const f16* p) {
  unsigned short s = __hip_atomic_load(
      reinterpret_cast<const unsigned short*>(p), __ATOMIC_RELAXED,
      __HIP_MEMORY_SCOPE_AGENT);
  union { unsigned short s; f16 f; } u;
  u.s = s;
  return (float)u.f;
}
__device__ __forceinline__ void astore2(f16* p, float v) {
  union { f16 f; unsigned short s; } u;
  u.f = (f16)v;
  __hip_atomic_store(reinterpret_cast<unsigned short*>(p), u.s,
                     __ATOMIC_RELAXED, __HIP_MEMORY_SCOPE_AGENT);
}
__device__ __forceinline__ float aloadf(const float* p) {
  return __hip_atomic_load(p, __ATOMIC_RELAXED, __HIP_MEMORY_SCOPE_AGENT);
}
__device__ __forceinline__ void astoref(float* p, float v) {
  __hip_atomic_store(p, v, __ATOMIC_RELAXED, __HIP_MEMORY_SCOPE_AGENT);
}

// ---- fp32 -> fp16 convert (x4 vectorized) ----------------------------------
__global__ void to_f16_4(const float* __restrict__ src, f16* __restrict__ dst,
                         int n4) {
  int i = blockIdx.x * 256 + threadIdx.x;
  if (i >= n4) return;
  float4 v = reinterpret_cast<const float4*>(src)[i];
  f16x4 o = {(f16)v.x, (f16)v.y, (f16)v.z, (f16)v.w};
  reinterpret_cast<f16x4*>(dst)[i] = o;
}

// ---- pack the 3 role weight images -----------------------------------------
// dst[which][bi][k0<32][row<48][kk<32] f16, dense. row = g*16 + jrow,
// j = bi*16 + jrow. which: 0 = W_hh[0], 1 = W_ih[1], 2 = W_hh[1].
__global__ void pack_w(const float* __restrict__ Whh,
                       const float* __restrict__ Wih, f16* __restrict__ dst) {
  const int id = blockIdx.x * 256 + threadIdx.x;  // 1,179,648 vec8 elems
  const int kkq = id & 3;
  const int rr = id >> 2;
  const int row = rr % 48;
  const int rest = rr / 48;
  const int k0 = rest & 31, bi = (rest >> 5) & 63, which = rest >> 11;
  const int g = row >> 4, jrow = row & 15;
  const float* base = (which == 0) ? Whh
                    : (which == 1) ? (Wih + (size_t)G * H)
                                   : (Whh + (size_t)G * H);
  const float* src =
      base + ((size_t)(g * H + bi * 16 + jrow)) * H + k0 * 32 + kkq * 8;
  float4 a = *reinterpret_cast<const float4*>(src);
  float4 b = *reinterpret_cast<const float4*>(src + 4);
  f16x8 o = {(f16)a.x, (f16)a.y, (f16)a.z, (f16)a.w,
             (f16)b.x, (f16)b.y, (f16)b.z, (f16)b.w};
  *reinterpret_cast<f16x8*>(dst + (size_t)id * 8) = o;
}

// ---- pack h0 into tiled layout [k0][b][kk] fp16 ----------------------------
__global__ void pack_h0f(const float* __restrict__ h0, f16* __restrict__ h1,
                         f16* __restrict__ h2) {
  const int id = blockIdx.x * 256 + threadIdx.x;  // 131072
  const int layer = id >> 16, b = (id >> 10) & 63, j = id & 1023;
  const size_t a = ((size_t)(j >> 5) * 64 + b) * 32 + (j & 31);
  const f16 v = (f16)h0[id];
  if (layer == 0) h1[a] = v; else h2[a] = v;
}

// ---- fp16 GEMM: C[M,N] = A @ B[N,K]^T + bias -------------------------------
// MODE 0: A row-major [M,K], C fp32 [M,N].
// MODE 2: logits. A is y2 in tiled per-t slabs ([t][k0][b][kk], 65536/t);
//         bm indexes t; write out[(b*(T-1)+t)*V + n] for t < T-1.
template <int MODE>
__global__ __launch_bounds__(256) void gemm_f16(
    const f16* __restrict__ A, const f16* __restrict__ Bm,
    const float* __restrict__ bias, float* __restrict__ C, int M, int N,
    int K) {
  __shared__ __align__(16) f16 As[64][48], Bs[64][48];

  const int tid = threadIdx.x;
  const int lane = tid & 63, wv = tid >> 6;
  const int bm = blockIdx.y, bn = blockIdx.x;
  const int srow = tid >> 2, sseg = (tid & 3) * 8;

  const f16* pA = (MODE == 2)
                      ? (A + (size_t)bm * 65536 + srow * 32 + sseg)
                      : (A + (size_t)(bm * 64 + srow) * K + sseg);
  const f16* pB = Bm + (size_t)(bn * 64 + srow) * K + sseg;

  f32x4 acc[4];
  const f32x4 zero = {0.f, 0.f, 0.f, 0.f};
#pragma unroll
  for (int nt = 0; nt < 4; ++nt) acc[nt] = zero;

  const int ar = wv * 16 + (lane & 15);
  const int kk = (lane >> 4) * 8;

  const int niter = K / 32;
  for (int ki = 0; ki < niter; ++ki) {
    int4 va = (MODE == 2) ? *reinterpret_cast<const int4*>(pA + ki * 2048)
                          : *reinterpret_cast<const int4*>(pA + ki * 32);
    int4 vb = *reinterpret_cast<const int4*>(pB + ki * 32);
    __syncthreads();
    *reinterpret_cast<int4*>(&As[srow][sseg]) = va;
    *reinterpret_cast<int4*>(&Bs[srow][sseg]) = vb;
    __syncthreads();

    f16x8 av = *reinterpret_cast<const f16x8*>(&As[ar][kk]);
#pragma unroll
    for (int nt = 0; nt < 4; ++nt) {
      f16x8 bv = *reinterpret_cast<const f16x8*>(&Bs[nt * 16 + (lane & 15)][kk]);
      acc[nt] = MFMA16(av, bv, acc[nt]);
    }
  }

  const int rbase = wv * 16 + (lane >> 4) * 4;
  const int cl = lane & 15;
#pragma unroll
  for (int nt = 0; nt < 4; ++nt) {
    const int n = bn * 64 + nt * 16 + cl;
    const float bv = bias[n];
#pragma unroll
    for (int r = 0; r < 4; ++r) {
      const int m = bm * 64 + rbase + r;
      const float v = acc[nt][r] + bv;
      if (MODE == 0) {
        C[(size_t)m * N + n] = v;
      } else {
        const int t = m >> 6, bb = m & 63;
        if (t < T - 1) C[((size_t)(bb * (T - 1) + t)) * V + n] = v;
      }
    }
  }
}

// ---- persistent 3-role GRU pipeline (fence-free) ---------------------------
// 192 blocks x 256 threads (cooperative). role = bx>>6, jb = bx&63.
// Interval i: L1 computes h1[t=i] (i<512); GX computes gx2[t=i-1] (1<=i<=512);
// L2 computes h2[t=i-2] + y2 row (2<=i<=513).
__global__ __launch_bounds__(256, 1) void gru_persist(
    const f16* __restrict__ pW, const float* __restrict__ G0,
    const int* __restrict__ X, const float* __restrict__ b_hh,
    const float* __restrict__ b_ih, f16* __restrict__ h1a,
    f16* __restrict__ h1b, f16* __restrict__ h2a, f16* __restrict__ h2b,
    float* __restrict__ gx2, f16* __restrict__ y2, int* __restrict__ bar) {
  __shared__ __align__(16) f16 Wt[55296];  // [k0<32][row<48][kk padded to 36]

  const int tid = threadIdx.x, bx = blockIdx.x;
  const int lane = tid & 63, wv = tid >> 6;
  const int l15 = lane & 15, kq = lane >> 4;
  const int role = bx >> 6, jb = bx & 63;

  // ---- stage this block's 96KB W image (dense global -> padded LDS) ----
  {
    const int2* src = reinterpret_cast<const int2*>(pW + (size_t)bx * 49152);
#pragma unroll
    for (int q = 0; q < 48; ++q) {
      const int flat = q * 256 + tid;   // 12288 int2
      const int k0r = flat >> 3, seg = flat & 7;
      *reinterpret_cast<int2*>(&Wt[k0r * 36 + seg * 4]) = src[flat];
    }
  }
  __syncthreads();

  const int j = jb * 16 + l15;
  float br_ = 0.f, bz_ = 0.f, bn_ = 0.f, bxr_ = 0.f, bxz_ = 0.f, bxn_ = 0.f;
  if (role == 0) {
    br_ = b_hh[j]; bz_ = b_hh[H + j]; bn_ = b_hh[2 * H + j];
  } else if (role == 2) {
    br_ = b_hh[G + j]; bz_ = b_hh[G + H + j]; bn_ = b_hh[G + 2 * H + j];
    bxr_ = b_ih[G + j]; bxz_ = b_ih[G + H + j]; bxn_ = b_ih[G + 2 * H + j];
  }

  f16* h1buf[2] = {h1a, h1b};
  f16* h2buf[2] = {h2a, h2b};
  const int aoff = (wv * 16 + l15) * 32 + kq * 8;
  const f16* wp = Wt + l15 * 36 + kq * 8;  // + k0*1728 + g*576
  const int bB = wv * 16 + kq * 4;
  const size_t hoff = (size_t)(j >> 5) * 2048 + (j & 31);

  for (int i = 0; i <= T + 1; ++i) {
    if (role == 0) {
      if (i < T) {  // ---- L1: h1[t=i] ----
        const f16* hin = h1buf[i & 1];
        f16* hout = h1buf[(i + 1) & 1];
        const f16* a = hin + aoff;
        f32x4 aR = {0, 0, 0, 0}, aZ = {0, 0, 0, 0}, aN = {0, 0, 0, 0};
#pragma unroll 8
        for (int k0 = 0; k0 < 32; ++k0) {
          f16x8 av = aload16(a + k0 * 2048);
          const f16* w = wp + k0 * 1728;
          aR = MFMA16(av, *reinterpret_cast<const f16x8*>(w), aR);
          aZ = MFMA16(av, *reinterpret_cast<const f16x8*>(w + 576), aZ);
          aN = MFMA16(av, *reinterpret_cast<const f16x8*>(w + 1152), aN);
        }
#pragma unroll
        for (int r = 0; r < 4; ++r) {
          const int b = bB + r;
          const float* gx = G0 + (size_t)X[b * T + i] * G;
          const float xr = gx[j], xz = gx[H + j], xn = gx[2 * H + j];
          const size_t ha = hoff + (size_t)b * 32;
          const float hp = aload2(hin + ha);
          const float rg = 1.f / (1.f + __expf(-(xr + aR[r] + br_)));
          const float zg = 1.f / (1.f + __expf(-(xz + aZ[r] + bz_)));
          const float ng = tanhf(xn + rg * (aN[r] + bn_));
          astore2(hout + ha, (1.f - zg) * ng + zg * hp);
        }
      }
    } else if (role == 1) {
      if (i >= 1 && i <= T) {  // ---- GX: gx2[t=i-1] = y1[t] @ W_ih1^T ----
        const int t = i - 1;
        const f16* a = h1buf[i & 1] + aoff;  // y1[t] = h1 after step t
        f32x4 aR = {0, 0, 0, 0}, aZ = {0, 0, 0, 0}, aN = {0, 0, 0, 0};
#pragma unroll 8
        for (int k0 = 0; k0 < 32; ++k0) {
          f16x8 av = aload16(a + k0 * 2048);
          const f16* w = wp + k0 * 1728;
          aR = MFMA16(av, *reinterpret_cast<const f16x8*>(w), aR);
          aZ = MFMA16(av, *reinterpret_cast<const f16x8*>(w + 576), aZ);
          aN = MFMA16(av, *reinterpret_cast<const f16x8*>(w + 1152), aN);
        }
        float* gdst = gx2 + ((size_t)(t & 1) * 64 + jb) * 3072;
#pragma unroll
        for (int r = 0; r < 4; ++r) {
          const int b = bB + r;
          astoref(gdst + b * 16 + l15, aR[r]);
          astoref(gdst + 1024 + b * 16 + l15, aZ[r]);
          astoref(gdst + 2048 + b * 16 + l15, aN[r]);
        }
      }
    } else {
      if (i >= 2) {  // ---- L2: h2[t=i-2] + y2 ----
        const int t = i - 2;
        const f16* hin = h2buf[i & 1];
        f16* hout = h2buf[(i + 1) & 1];
        const float* gsrc = gx2 + ((size_t)(t & 1) * 64 + jb) * 3072;
        const f16* a = hin + aoff;
        f32x4 aR = {0, 0, 0, 0}, aZ = {0, 0, 0, 0}, aN = {0, 0, 0, 0};
#pragma unroll 8
        for (int k0 = 0; k0 < 32; ++k0) {
          f16x8 av = aload16(a + k0 * 2048);
          const f16* w = wp + k0 * 1728;
          aR = MFMA16(av, *reinterpret_cast<const f16x8*>(w), aR);
          aZ = MFMA16(av, *reinterpret_cast<const f16x8*>(w + 576), aZ);
          aN = MFMA16(av, *reinterpret_cast<const f16x8*>(w + 1152), aN);
        }
#pragma unroll
        for (int r = 0; r < 4; ++r) {
          const int b = bB + r;
          const float xr = aloadf(gsrc + b * 16 + l15);
          const float xz = aloadf(gsrc + 1024 + b * 16 + l15);
          const float xn = aloadf(gsrc + 2048 + b * 16 + l15);
          const size_t ha = hoff + (size_t)b * 32;
          const float hp = aload2(hin + ha);
          const float rg = 1.f / (1.f + __expf(-(xr + bxr_ + aR[r] + br_)));
          const float zg = 1.f / (1.f + __expf(-(xz + bxz_ + aZ[r] + bz_)));
          const float ng = tanhf(xn + bxn_ + rg * (aN[r] + bn_));
          const float hv = (1.f - zg) * ng + zg * hp;
          astore2(hout + ha, hv);
          y2[(size_t)t * 65536 + ha] = (f16)hv;  // plain store (read post-kernel)
        }
      }
    }

    // ---- fence-free flag barrier ----
    // __syncthreads emits s_waitcnt vmcnt(0) per wave before s_barrier, so all
    // bypass (sc0|sc1) stores are acked at the coherent point before the flag.
    asm volatile("" ::: "memory");
    __syncthreads();
    const int ph = i + 1;
    if (tid == 0)
      __hip_atomic_store(&bar[bx], ph, __ATOMIC_RELAXED,
                         __HIP_MEMORY_SCOPE_AGENT);
    if (tid < NBLK) {
      while (__hip_atomic_load(&bar[tid], __ATOMIC_RELAXED,
                               __HIP_MEMORY_SCOPE_AGENT) < ph) {
        __builtin_amdgcn_s_sleep(1);
      }
    }
    __syncthreads();
    asm volatile("" ::: "memory");
  }
}

}  // namespace

// ============================================================================
extern "C" void kernel_launch(void* const* d_in, const int* in_sizes, int n_in,
                              void* d_out, int out_size, void* d_ws,
                              size_t ws_size, hipStream_t stream) {
  const int* X = (const int*)d_in[0];
  const float* h0 = (const float*)d_in[1];
  const float* emb = (const float*)d_in[2];
  const float* W_ih = (const float*)d_in[3];
  const float* W_hh = (const float*)d_in[4];
  const float* b_ih = (const float*)d_in[5];
  const float* b_hh = (const float*)d_in[6];
  const float* W_out = (const float*)d_in[7];
  const float* b_out = (const float*)d_in[8];
  float* out = (float*)d_out;
  (void)in_sizes; (void)n_in; (void)out_size; (void)ws_size;

  // ---- workspace (~94 MB) ----
  char* p = (char*)d_ws;
  auto alloc = [&](size_t bytes) {
    char* q = p;
    p += (bytes + 255) & ~(size_t)255;
    return q;
  };
  f16* pW = (f16*)alloc((size_t)3 * 64 * 49152 * 2);  // 18 MB (3 role images)
  float* G0 = (float*)alloc((size_t)V * G * 4);       // 3 MB
  f16* emb16 = (f16*)alloc((size_t)V * H * 2);
  f16* wih0_16 = (f16*)alloc((size_t)G * H * 2);      // 6 MB
  f16* wout16 = (f16*)alloc((size_t)V * H * 2);
  f16* h1a = (f16*)alloc((size_t)B * H * 2);
  f16* h1b = (f16*)alloc((size_t)B * H * 2);
  f16* h2a = (f16*)alloc((size_t)B * H * 2);
  f16* h2b = (f16*)alloc((size_t)B * H * 2);
  float* gx2 = (float*)alloc((size_t)2 * 64 * 3072 * 4);  // 1.5 MB
  f16* y2 = (f16*)alloc((size_t)T * B * H * 2);           // 64 MB
  int* bar = (int*)alloc(256 * 4);
  // NOTE: bar starts 0xAA-poisoned = negative ints; poll condition (< phase)
  // treats that as "not yet arrived", so no explicit zeroing is needed.

  // ---- one-time converts / packs / G0 ----
  to_f16_4<<<(V * H / 4 + 255) / 256, 256, 0, stream>>>(emb, emb16, V * H / 4);
  to_f16_4<<<(G * H / 4 + 255) / 256, 256, 0, stream>>>(W_ih, wih0_16,
                                                        G * H / 4);
  to_f16_4<<<(V * H / 4 + 255) / 256, 256, 0, stream>>>(W_out, wout16,
                                                        V * H / 4);
  pack_w<<<4608, 256, 0, stream>>>(W_hh, W_ih, pW);
  pack_h0f<<<512, 256, 0, stream>>>(h0, h1a, h2a);
  gemm_f16<0><<<dim3(G / 64, V / 64), 256, 0, stream>>>(emb16, wih0_16, b_ih,
                                                        G0, V, G, H);

  // ---- persistent 3-role pipeline (cooperative: guarantees co-residency) ----
  {
    const f16* a0 = pW; const float* a1 = G0; const int* a2 = X;
    const float* a3 = b_hh; const float* a4 = b_ih;
    f16* a5 = h1a; f16* a6 = h1b; f16* a7 = h2a; f16* a8 = h2b;
    float* a9 = gx2; f16* a10 = y2; int* a11 = bar;
    void* args[] = {&a0, &a1, &a2, &a3, &a4, &a5, &a6,
                    &a7, &a8, &a9, &a10, &a11};
    hipLaunchCooperativeKernel((const void*)gru_persist, dim3(NBLK), dim3(256),
                               args, 0, stream);
  }

  // ---- logits = y2 @ W_out^T + b_out (drop t = T-1 rows) ----
  gemm_f16<2><<<dim3(V / 64, T), 256, 0, stream>>>(y2, wout16, b_out, out,
                                                   T * B, V, H);
}

// Round 8
// 9703.128 us; speedup vs baseline: 3.7057x; 1.0419x over previous
//
#include <hip/hip_runtime.h>
#include <stdint.h>

// ============================================================================
// CharNN: 2-layer GRU char LM (B=64, T=512, V=256, E=H=1024) on MI355X.
// Round 8: round-6 base (known good) + depth-8 PREFETCH RING in the k-loop.
//  * Round 6 (passing, 10.1ms): every bypass load chained -> ~17us serialized
//    k-loop. Round 7 (16-wide batches) broke correctness (absmax 1.42) --
//    suspected compiler motion of relaxed agent atomics across the workgroup
//    fence when given large schedulable batches.
//  * This round: ring[8] prefetch -- issue 8, then consume-1/issue-1 per k0.
//    Tight per-iteration chaining (no free-floating batch), atomics in strict
//    source order, progressive vmcnt waits (oldest-first per m135).
//  * Epilogues/barrier/everything else EXACTLY round 6 for failure isolation.
// ============================================================================

namespace {

constexpr int B = 64, T = 512, V = 256, H = 1024, G = 3072;  // G = 3*H
constexpr int NBLK = 192;

typedef _Float16 f16;
typedef unsigned long long u64;
typedef f16 f16x8 __attribute__((ext_vector_type(8)));
typedef f16 f16x4 __attribute__((ext_vector_type(4)));
typedef float f32x4 __attribute__((ext_vector_type(4)));

#define MFMA16(av, bv, acc) __builtin_amdgcn_mfma_f32_16x16x32_f16(av, bv, acc, 0, 0, 0)

// ---- relaxed agent-scope (LLC-coherent, no-fence) access helpers -----------
__device__ __forceinline__ f16x8 aload16(const f16* p) {
  u64 lo = __hip_atomic_load(reinterpret_cast<const u64*>(p), __ATOMIC_RELAXED,
                             __HIP_MEMORY_SCOPE_AGENT);
  u64 hi = __hip_atomic_load(reinterpret_cast<const u64*>(p) + 1,
                             __ATOMIC_RELAXED, __HIP_MEMORY_SCOPE_AGENT);
  union { u64 q[2]; f16x8 v; } u;
  u.q[0] = lo; u.q[1] = hi;
  return u.v;
}
__device__ __forceinline__ float aload2(const f16* p) {
  unsigned short s = __hip_atomic_load(
      reinterpret_cast<const unsigned short*>(p), __ATOMIC_RELAXED,
      __HIP_MEMORY_SCOPE_AGENT);
  union { unsigned short s; f16 f; } u;
  u.s = s;
  return (float)u.f;
}
__device__ __forceinline__ void astore2(f16* p, float v) {
  union { f16 f; unsigned short s; } u;
  u.f = (f16)v;
  __hip_atomic_store(reinterpret_cast<unsigned short*>(p), u.s,
                     __ATOMIC_RELAXED, __HIP_MEMORY_SCOPE_AGENT);
}
__device__ __forceinline__ float aloadf(const float* p) {
  return __hip_atomic_load(p, __ATOMIC_RELAXED, __HIP_MEMORY_SCOPE_AGENT);
}
__device__ __forceinline__ void astoref(float* p, float v) {
  __hip_atomic_store(p, v, __ATOMIC_RELAXED, __HIP_MEMORY_SCOPE_AGENT);
}

// ---- 48-row x K=1024 MFMA block with depth-8 prefetch ring -----------------
// acc += W(LDS) * h(bypass). Each iteration consumes ring[k0&7] and re-issues
// the k0+8 load into that slot -> 8 outstanding, strict source order.
__device__ __forceinline__ void mm48(const f16* a, const f16* wp, f32x4& aR,
                                     f32x4& aZ, f32x4& aN) {
  f16x8 ring[8];
#pragma unroll
  for (int q = 0; q < 8; ++q) ring[q] = aload16(a + q * 2048);
#pragma unroll
  for (int k0 = 0; k0 < 32; ++k0) {
    f16x8 av = ring[k0 & 7];
    if (k0 + 8 < 32) ring[k0 & 7] = aload16(a + (k0 + 8) * 2048);
    const f16* w = wp + k0 * 1728;
    aR = MFMA16(av, *reinterpret_cast<const f16x8*>(w), aR);
    aZ = MFMA16(av, *reinterpret_cast<const f16x8*>(w + 576), aZ);
    aN = MFMA16(av, *reinterpret_cast<const f16x8*>(w + 1152), aN);
  }
}

// ---- fp32 -> fp16 convert (x4 vectorized) ----------------------------------
__global__ void to_f16_4(const float* __restrict__ src, f16* __restrict__ dst,
                         int n4) {
  int i = blockIdx.x * 256 + threadIdx.x;
  if (i >= n4) return;
  float4 v = reinterpret_cast<const float4*>(src)[i];
  f16x4 o = {(f16)v.x, (f16)v.y, (f16)v.z, (f16)v.w};
  reinterpret_cast<f16x4*>(dst)[i] = o;
}

// ---- pack the 3 role weight images -----------------------------------------
// dst[which][bi][k0<32][row<48][kk<32] f16, dense. row = g*16 + jrow,
// j = bi*16 + jrow. which: 0 = W_hh[0], 1 = W_ih[1], 2 = W_hh[1].
__global__ void pack_w(const float* __restrict__ Whh,
                       const float* __restrict__ Wih, f16* __restrict__ dst) {
  const int id = blockIdx.x * 256 + threadIdx.x;  // 1,179,648 vec8 elems
  const int kkq = id & 3;
  const int rr = id >> 2;
  const int row = rr % 48;
  const int rest = rr / 48;
  const int k0 = rest & 31, bi = (rest >> 5) & 63, which = rest >> 11;
  const int g = row >> 4, jrow = row & 15;
  const float* base = (which == 0) ? Whh
                    : (which == 1) ? (Wih + (size_t)G * H)
                                   : (Whh + (size_t)G * H);
  const float* src =
      base + ((size_t)(g * H + bi * 16 + jrow)) * H + k0 * 32 + kkq * 8;
  float4 a = *reinterpret_cast<const float4*>(src);
  float4 b = *reinterpret_cast<const float4*>(src + 4);
  f16x8 o = {(f16)a.x, (f16)a.y, (f16)a.z, (f16)a.w,
             (f16)b.x, (f16)b.y, (f16)b.z, (f16)b.w};
  *reinterpret_cast<f16x8*>(dst + (size_t)id * 8) = o;
}

// ---- pack h0 into tiled layout [k0][b][kk] fp16 ----------------------------
__global__ void pack_h0f(const float* __restrict__ h0, f16* __restrict__ h1,
                         f16* __restrict__ h2) {
  const int id = blockIdx.x * 256 + threadIdx.x;  // 131072
  const int layer = id >> 16, b = (id >> 10) & 63, j = id & 1023;
  const size_t a = ((size_t)(j >> 5) * 64 + b) * 32 + (j & 31);
  const f16 v = (f16)h0[id];
  if (layer == 0) h1[a] = v; else h2[a] = v;
}

// ---- fp16 GEMM: C[M,N] = A @ B[N,K]^T + bias -------------------------------
// MODE 0: A row-major [M,K], C fp32 [M,N].
// MODE 2: logits. A is y2 in tiled per-t slabs ([t][k0][b][kk], 65536/t);
//         bm indexes t; write out[(b*(T-1)+t)*V + n] for t < T-1.
template <int MODE>
__global__ __launch_bounds__(256) void gemm_f16(
    const f16* __restrict__ A, const f16* __restrict__ Bm,
    const float* __restrict__ bias, float* __restrict__ C, int M, int N,
    int K) {
  __shared__ __align__(16) f16 As[64][48], Bs[64][48];

  const int tid = threadIdx.x;
  const int lane = tid & 63, wv = tid >> 6;
  const int bm = blockIdx.y, bn = blockIdx.x;
  const int srow = tid >> 2, sseg = (tid & 3) * 8;

  const f16* pA = (MODE == 2)
                      ? (A + (size_t)bm * 65536 + srow * 32 + sseg)
                      : (A + (size_t)(bm * 64 + srow) * K + sseg);
  const f16* pB = Bm + (size_t)(bn * 64 + srow) * K + sseg;

  f32x4 acc[4];
  const f32x4 zero = {0.f, 0.f, 0.f, 0.f};
#pragma unroll
  for (int nt = 0; nt < 4; ++nt) acc[nt] = zero;

  const int ar = wv * 16 + (lane & 15);
  const int kk = (lane >> 4) * 8;

  const int niter = K / 32;
  for (int ki = 0; ki < niter; ++ki) {
    int4 va = (MODE == 2) ? *reinterpret_cast<const int4*>(pA + ki * 2048)
                          : *reinterpret_cast<const int4*>(pA + ki * 32);
    int4 vb = *reinterpret_cast<const int4*>(pB + ki * 32);
    __syncthreads();
    *reinterpret_cast<int4*>(&As[srow][sseg]) = va;
    *reinterpret_cast<int4*>(&Bs[srow][sseg]) = vb;
    __syncthreads();

    f16x8 av = *reinterpret_cast<const f16x8*>(&As[ar][kk]);
#pragma unroll
    for (int nt = 0; nt < 4; ++nt) {
      f16x8 bv = *reinterpret_cast<const f16x8*>(&Bs[nt * 16 + (lane & 15)][kk]);
      acc[nt] = MFMA16(av, bv, acc[nt]);
    }
  }

  const int rbase = wv * 16 + (lane >> 4) * 4;
  const int cl = lane & 15;
#pragma unroll
  for (int nt = 0; nt < 4; ++nt) {
    const int n = bn * 64 + nt * 16 + cl;
    const float bv = bias[n];
#pragma unroll
    for (int r = 0; r < 4; ++r) {
      const int m = bm * 64 + rbase + r;
      const float v = acc[nt][r] + bv;
      if (MODE == 0) {
        C[(size_t)m * N + n] = v;
      } else {
        const int t = m >> 6, bb = m & 63;
        if (t < T - 1) C[((size_t)(bb * (T - 1) + t)) * V + n] = v;
      }
    }
  }
}

// ---- persistent 3-role GRU pipeline (fence-free) ---------------------------
// 192 blocks x 256 threads (cooperative). role = bx>>6, jb = bx&63.
// Interval i: L1 computes h1[t=i] (i<512); GX computes gx2[t=i-1] (1<=i<=512);
// L2 computes h2[t=i-2] + y2 row (2<=i<=513).
__global__ __launch_bounds__(256, 1) void gru_persist(
    const f16* __restrict__ pW, const float* __restrict__ G0,
    const int* __restrict__ X, const float* __restrict__ b_hh,
    const float* __restrict__ b_ih, f16* __restrict__ h1a,
    f16* __restrict__ h1b, f16* __restrict__ h2a, f16* __restrict__ h2b,
    float* __restrict__ gx2, f16* __restrict__ y2, int* __restrict__ bar) {
  __shared__ __align__(16) f16 Wt[55296];  // [k0<32][row<48][kk padded to 36]

  const int tid = threadIdx.x, bx = blockIdx.x;
  const int lane = tid & 63, wv = tid >> 6;
  const int l15 = lane & 15, kq = lane >> 4;
  const int role = bx >> 6, jb = bx & 63;

  // ---- stage this block's 96KB W image (dense global -> padded LDS) ----
  {
    const int2* src = reinterpret_cast<const int2*>(pW + (size_t)bx * 49152);
#pragma unroll
    for (int q = 0; q < 48; ++q) {
      const int flat = q * 256 + tid;   // 12288 int2
      const int k0r = flat >> 3, seg = flat & 7;
      *reinterpret_cast<int2*>(&Wt[k0r * 36 + seg * 4]) = src[flat];
    }
  }
  __syncthreads();

  const int j = jb * 16 + l15;
  float br_ = 0.f, bz_ = 0.f, bn_ = 0.f, bxr_ = 0.f, bxz_ = 0.f, bxn_ = 0.f;
  if (role == 0) {
    br_ = b_hh[j]; bz_ = b_hh[H + j]; bn_ = b_hh[2 * H + j];
  } else if (role == 2) {
    br_ = b_hh[G + j]; bz_ = b_hh[G + H + j]; bn_ = b_hh[G + 2 * H + j];
    bxr_ = b_ih[G + j]; bxz_ = b_ih[G + H + j]; bxn_ = b_ih[G + 2 * H + j];
  }

  f16* h1buf[2] = {h1a, h1b};
  f16* h2buf[2] = {h2a, h2b};
  const int aoff = (wv * 16 + l15) * 32 + kq * 8;
  const f16* wp = Wt + l15 * 36 + kq * 8;  // + k0*1728 + g*576
  const int bB = wv * 16 + kq * 4;
  const size_t hoff = (size_t)(j >> 5) * 2048 + (j & 31);

  for (int i = 0; i <= T + 1; ++i) {
    if (role == 0) {
      if (i < T) {  // ---- L1: h1[t=i] ----
        const f16* hin = h1buf[i & 1];
        f16* hout = h1buf[(i + 1) & 1];
        f32x4 aR = {0, 0, 0, 0}, aZ = {0, 0, 0, 0}, aN = {0, 0, 0, 0};
        mm48(hin + aoff, wp, aR, aZ, aN);
        // epilogue EXACTLY as round 6 (per-r interleaved loads)
#pragma unroll
        for (int r = 0; r < 4; ++r) {
          const int b = bB + r;
          const float* gx = G0 + (size_t)X[b * T + i] * G;
          const float xr = gx[j], xz = gx[H + j], xn = gx[2 * H + j];
          const size_t ha = hoff + (size_t)b * 32;
          const float hp = aload2(hin + ha);
          const float rg = 1.f / (1.f + __expf(-(xr + aR[r] + br_)));
          const float zg = 1.f / (1.f + __expf(-(xz + aZ[r] + bz_)));
          const float ng = tanhf(xn + rg * (aN[r] + bn_));
          astore2(hout + ha, (1.f - zg) * ng + zg * hp);
        }
      }
    } else if (role == 1) {
      if (i >= 1 && i <= T) {  // ---- GX: gx2[t=i-1] = y1[t] @ W_ih1^T ----
        const int t = i - 1;
        f32x4 aR = {0, 0, 0, 0}, aZ = {0, 0, 0, 0}, aN = {0, 0, 0, 0};
        mm48(h1buf[i & 1] + aoff, wp, aR, aZ, aN);  // y1[t] = h1 after step t
        float* gdst = gx2 + ((size_t)(t & 1) * 64 + jb) * 3072;
#pragma unroll
        for (int r = 0; r < 4; ++r) {
          const int b = bB + r;
          astoref(gdst + b * 16 + l15, aR[r]);
          astoref(gdst + 1024 + b * 16 + l15, aZ[r]);
          astoref(gdst + 2048 + b * 16 + l15, aN[r]);
        }
      }
    } else {
      if (i >= 2) {  // ---- L2: h2[t=i-2] + y2 ----
        const int t = i - 2;
        const f16* hin = h2buf[i & 1];
        f16* hout = h2buf[(i + 1) & 1];
        const float* gsrc = gx2 + ((size_t)(t & 1) * 64 + jb) * 3072;
        f32x4 aR = {0, 0, 0, 0}, aZ = {0, 0, 0, 0}, aN = {0, 0, 0, 0};
        mm48(hin + aoff, wp, aR, aZ, aN);
        // epilogue EXACTLY as round 6 (per-r interleaved loads)
#pragma unroll
        for (int r = 0; r < 4; ++r) {
          const int b = bB + r;
          const float xr = aloadf(gsrc + b * 16 + l15);
          const float xz = aloadf(gsrc + 1024 + b * 16 + l15);
          const float xn = aloadf(gsrc + 2048 + b * 16 + l15);
          const size_t ha = hoff + (size_t)b * 32;
          const float hp = aload2(hin + ha);
          const float rg = 1.f / (1.f + __expf(-(xr + bxr_ + aR[r] + br_)));
          const float zg = 1.f / (1.f + __expf(-(xz + bxz_ + aZ[r] + bz_)));
          const float ng = tanhf(xn + bxn_ + rg * (aN[r] + bn_));
          const float hv = (1.f - zg) * ng + zg * hp;
          astore2(hout + ha, hv);
          y2[(size_t)t * 65536 + ha] = (f16)hv;  // plain (read post-kernel)
        }
      }
    }

    // ---- fence-free flag barrier (exactly round 6) ----
    asm volatile("" ::: "memory");
    __syncthreads();
    const int ph = i + 1;
    if (tid == 0)
      __hip_atomic_store(&bar[bx], ph, __ATOMIC_RELAXED,
                         __HIP_MEMORY_SCOPE_AGENT);
    if (tid < NBLK) {
      while (__hip_atomic_load(&bar[tid], __ATOMIC_RELAXED,
                               __HIP_MEMORY_SCOPE_AGENT) < ph) {
        __builtin_amdgcn_s_sleep(1);
      }
    }
    __syncthreads();
    asm volatile("" ::: "memory");
  }
}

}  // namespace

// ============================================================================
extern "C" void kernel_launch(void* const* d_in, const int* in_sizes, int n_in,
                              void* d_out, int out_size, void* d_ws,
                              size_t ws_size, hipStream_t stream) {
  const int* X = (const int*)d_in[0];
  const float* h0 = (const float*)d_in[1];
  const float* emb = (const float*)d_in[2];
  const float* W_ih = (const float*)d_in[3];
  const float* W_hh = (const float*)d_in[4];
  const float* b_ih = (const float*)d_in[5];
  const float* b_hh = (const float*)d_in[6];
  const float* W_out = (const float*)d_in[7];
  const float* b_out = (const float*)d_in[8];
  float* out = (float*)d_out;
  (void)in_sizes; (void)n_in; (void)out_size; (void)ws_size;

  // ---- workspace (~94 MB) ----
  char* p = (char*)d_ws;
  auto alloc = [&](size_t bytes) {
    char* q = p;
    p += (bytes + 255) & ~(size_t)255;
    return q;
  };
  f16* pW = (f16*)alloc((size_t)3 * 64 * 49152 * 2);  // 18 MB (3 role images)
  float* G0 = (float*)alloc((size_t)V * G * 4);       // 3 MB
  f16* emb16 = (f16*)alloc((size_t)V * H * 2);
  f16* wih0_16 = (f16*)alloc((size_t)G * H * 2);      // 6 MB
  f16* wout16 = (f16*)alloc((size_t)V * H * 2);
  f16* h1a = (f16*)alloc((size_t)B * H * 2);
  f16* h1b = (f16*)alloc((size_t)B * H * 2);
  f16* h2a = (f16*)alloc((size_t)B * H * 2);
  f16* h2b = (f16*)alloc((size_t)B * H * 2);
  float* gx2 = (float*)alloc((size_t)2 * 64 * 3072 * 4);  // 1.5 MB
  f16* y2 = (f16*)alloc((size_t)T * B * H * 2);           // 64 MB
  int* bar = (int*)alloc(256 * 4);
  // NOTE: bar starts 0xAA-poisoned = negative ints; poll condition (< phase)
  // treats that as "not yet arrived", so no explicit zeroing is needed.

  // ---- one-time converts / packs / G0 ----
  to_f16_4<<<(V * H / 4 + 255) / 256, 256, 0, stream>>>(emb, emb16, V * H / 4);
  to_f16_4<<<(G * H / 4 + 255) / 256, 256, 0, stream>>>(W_ih, wih0_16,
                                                        G * H / 4);
  to_f16_4<<<(V * H / 4 + 255) / 256, 256, 0, stream>>>(W_out, wout16,
                                                        V * H / 4);
  pack_w<<<4608, 256, 0, stream>>>(W_hh, W_ih, pW);
  pack_h0f<<<512, 256, 0, stream>>>(h0, h1a, h2a);
  gemm_f16<0><<<dim3(G / 64, V / 64), 256, 0, stream>>>(emb16, wih0_16, b_ih,
                                                        G0, V, G, H);

  // ---- persistent 3-role pipeline (cooperative: guarantees co-residency) ----
  {
    const f16* a0 = pW; const float* a1 = G0; const int* a2 = X;
    const float* a3 = b_hh; const float* a4 = b_ih;
    f16* a5 = h1a; f16* a6 = h1b; f16* a7 = h2a; f16* a8 = h2b;
    float* a9 = gx2; f16* a10 = y2; int* a11 = bar;
    void* args[] = {&a0, &a1, &a2, &a3, &a4, &a5, &a6,
                    &a7, &a8, &a9, &a10, &a11};
    hipLaunchCooperativeKernel((const void*)gru_persist, dim3(NBLK), dim3(256),
                               args, 0, stream);
  }

  // ---- logits = y2 @ W_out^T + b_out (drop t = T-1 rows) ----
  gemm_f16<2><<<dim3(V / 64, T), 256, 0, stream>>>(y2, wout16, b_out, out,
                                                   T * B, V, H);
}